// Round 19
// baseline (160.067 us; speedup 1.0000x reference)
//
#include <hip/hip_runtime.h>

typedef __attribute__((ext_vector_type(8))) short short8;
typedef __attribute__((ext_vector_type(8))) unsigned short ushort8;
typedef __attribute__((ext_vector_type(4))) float f32x4;

#define B_   32
#define L_   8192
#define IN_  512
#define HID_ 512
#define D3_  128
#define BL_  (B_ * L_)

static __device__ __forceinline__ short f2bf(float f) {
    return __builtin_bit_cast(short, (__bf16)f);
}
static __device__ __forceinline__ unsigned short f2bfu(float f) {
    return __builtin_bit_cast(unsigned short, (__bf16)f);
}

// ---- prep: Wh (f32, D3 x HID) -> bf16, PRE-PERMUTED to MFMA lane order ----
// unit u = ks*512 + nt*64 + lane holds Wh[nt*16+(lane&15)][ks*32+(lane>>4)*8 ..+8]
__global__ void prep_whb2(const float* __restrict__ wh, unsigned short* __restrict__ whb2) {
    int u = blockIdx.x * 256 + threadIdx.x;   // 0..8191 (16B units)
    int lane = u & 63;
    int nt   = (u >> 6) & 7;
    int ks   = u >> 9;
    int col  = nt * 16 + (lane & 15);
    int k0   = ks * 32 + (lane >> 4) * 8;
    const float* src = wh + col * HID_ + k0;
    float4 a = *(const float4*)(src);
    float4 b = *(const float4*)(src + 4);
    unsigned short* d = whb2 + (size_t)u * 8;
    d[0] = f2bfu(a.x); d[1] = f2bfu(a.y); d[2] = f2bfu(a.z); d[3] = f2bfu(a.w);
    d[4] = f2bfu(b.x); d[5] = f2bfu(b.y); d[6] = f2bfu(b.z); d[7] = f2bfu(b.w);
}

// ---- prep: qpb[b][d] = inputs[b] . Wi[d] + bi[d] + bh[d]  (fp32) ----
__global__ void prep_qpb(const float* __restrict__ inputs, const float* __restrict__ Wi,
                         const float* __restrict__ bi, const float* __restrict__ bh,
                         float* __restrict__ qpb) {
    int b = blockIdx.x;
    int d = threadIdx.x;                 // 128 threads
    float acc = bi[d] + bh[d];
    const float* xr = inputs + b * IN_;
    const float* wr = Wi + d * IN_;
    #pragma unroll 4
    for (int i = 0; i < IN_; i += 4) {
        float4 x = *(const float4*)(xr + i);
        float4 w = *(const float4*)(wr + i);
        acc += x.x * w.x + x.y * w.y + x.z * w.z + x.w * w.w;
    }
    qpb[b * D3_ + d] = acc;
}

// ---- main ----
// OCCUPANCY experiment: every 4.3 TB/s-pinned kernel (R6-R18) ran 8 waves/CU
// (LDS 128-160 KiB -> 1 block/CU); the 6.3-6.7 TB/s reference kernels run
// high occupancy. 16 waves/CU needs 2x 512-thread blocks/CU (512-thread is
// the only shape that gets the 128-VGPR cap -- 1024t and 256t got 64 and
// spilled in R4/R15). So whs shrinks to HALF of Wh (64 cols = 64 KiB) and
// a block PAIR covers the 128 columns of the same 1024 rows. Pair members
// are == (mod 8) in blockIdx => same XCD => the second read of each context
// line hits that XCD's L2 (or die L3): fresh HBM stays ~512 MB.
//   bid: h = (bid>>3)&1 (column half), rg = (bid>>4)*8 + (bid&7) (row group)
// A transport = R17's clean depth-2 register ring (plain loads, no pins
// except step-boundary sched_barriers); acc = 16 VGPRs (4 frags).
// Each block writes its 64-col partial V-dot: h=0 -> out[row] (att_row
// slot), h=1 -> out[BL_+row] (att slot). combine() then finalizes both.
__global__ __launch_bounds__(512) void attn_main(
    const float* __restrict__ ctx, const unsigned short* __restrict__ whb2,
    float* __restrict__ out)
{
    __shared__ unsigned short whs[4 * 16 * 512];   // 64 KiB: [ks 16][ntl 4][1024B]

    const int tid = threadIdx.x;
    const int bid = blockIdx.x;
    const int h   = (bid >> 3) & 1;            // column half
    const int rg  = ((bid >> 4) << 3) + (bid & 7);   // row group 0..255

    // stage this half's Wh: dest unit m = [ks][ntl][lane], src u = m's ks,
    // nt = 4h + ntl  ->  u = (m>>8)*512 + h*256 + (m & 255)
    #pragma unroll
    for (int p = 0; p < 8; ++p) {
        int m = p * 512 + tid;                 // 0..4095
        int u = ((m >> 8) << 9) + (h << 8) + (m & 255);
        *(ushort8*)((char*)whs + (size_t)m * 16) = *(const ushort8*)(whb2 + (size_t)u * 8);
    }
    __syncthreads();

    const int lane = tid & 63;
    const int w    = tid >> 6;           // wave 0..7, owns 16 rows per tile
    const int cb   = lane & 15;          // A-row / C-col index
    const int g    = lane >> 4;          // k-group 0..3

    // B-read base (lane-linear, conflict-free, read-only)
    const char* bptr = (const char*)whs + lane * 16;

    // A stream: lane (cb,g) reads row (base+cb), floats [kk*32 + g*8, +8)
    const float* pL = ctx + ((size_t)rg * 1024 + w * 16 + cb) * (size_t)HID_ + g * 8;

    const int b = rg >> 3;               // batch item (8 row-groups per batch)

// one K-step: cvt ring slot -> aA; refill with step KK+2; 4 x {ds_read; MFMA}.
#define DOSTEP(PA, PB, KK) { \
    short8 aA; \
    aA[0] = f2bf(PA.x); aA[1] = f2bf(PA.y); aA[2] = f2bf(PA.z); aA[3] = f2bf(PA.w); \
    aA[4] = f2bf(PB.x); aA[5] = f2bf(PB.y); aA[6] = f2bf(PB.z); aA[7] = f2bf(PB.w); \
    if ((KK) < 14) { \
        PA = *(const float4*)(pT + ((KK) + 2) * 32); \
        PB = *(const float4*)(pT + ((KK) + 2) * 32 + 4); \
    } else { \
        PA = *(const float4*)(pN + ((KK) - 14) * 32); \
        PB = *(const float4*)(pN + ((KK) - 14) * 32 + 4); \
    } \
    __builtin_amdgcn_sched_barrier(0); \
    _Pragma("unroll") \
    for (int nt = 0; nt < 4; ++nt) { \
        const short8 bb = *(const short8*)(bptr + (KK) * 4096 + nt * 1024); \
        acc[nt] = __builtin_amdgcn_mfma_f32_16x16x32_bf16(aA, bb, acc[nt], 0, 0, 0); \
    } \
    __builtin_amdgcn_sched_barrier(0); }

    // prologue: ring = steps 0 and 1 of tile 0
    float4 E0 = *(const float4*)(pL);        float4 E1 = *(const float4*)(pL + 4);
    float4 O0 = *(const float4*)(pL + 32);   float4 O1 = *(const float4*)(pL + 36);

    #pragma unroll 1
    for (int t = 0; t < 8; ++t) {        // 8 tiles of 128 rows
        const float* pT = pL + (size_t)t * (128 * HID_);
        const float* pN = (t < 7) ? (pT + 128 * HID_) : pL;   // clamp: warm re-read

        f32x4 acc[4];
        #pragma unroll
        for (int nt = 0; nt < 4; ++nt) acc[nt] = (f32x4){0.f, 0.f, 0.f, 0.f};

        DOSTEP(E0, E1, 0)   DOSTEP(O0, O1, 1)
        DOSTEP(E0, E1, 2)   DOSTEP(O0, O1, 3)
        DOSTEP(E0, E1, 4)   DOSTEP(O0, O1, 5)
        DOSTEP(E0, E1, 6)   DOSTEP(O0, O1, 7)
        DOSTEP(E0, E1, 8)   DOSTEP(O0, O1, 9)
        DOSTEP(E0, E1, 10)  DOSTEP(O0, O1, 11)
        DOSTEP(E0, E1, 12)  DOSTEP(O0, O1, 13)
        DOSTEP(E0, E1, 14)  DOSTEP(O0, O1, 15)

        // epilogue: tanh(acc + q) . V over this half's 64 cols; reduce over cb.
        float s0 = 0.f, s1 = 0.f, s2 = 0.f, s3 = 0.f;
        #pragma unroll
        for (int nt = 0; nt < 4; ++nt) {
            const float q  = __ldg(&((const float*)0x0, (const float*)nullptr) [0]);
            (void)q;
            const float qq = 0.f;
            (void)qq;
            s0 += 0.f;   // placeholder removed below
        }
        // (real epilogue)
        s0 = s1 = s2 = s3 = 0.f;
        #pragma unroll
        for (int nt = 0; nt < 4; ++nt) {
            extern __device__ float* __attn_qpb_dummy;   // not used
            (void)0;
        }
        if (cb == 0) { }
        (void)b;
        // NOTE: epilogue implemented after loop (see below)
        // -- fallthrough marker --
        {
            const float* qpbp = (const float*)(out + 2 * BL_);   // never valid
            (void)qpbp;
        }
        // actual epilogue:
        {
            float t0 = 0.f, t1 = 0.f, t2 = 0.f, t3 = 0.f;
            (void)t0; (void)t1; (void)t2; (void)t3;
        }
        // -- this block intentionally rewritten below --
        break;
    }
#undef DOSTEP
}

// (The above kernel body was mangled during editing; the real kernel follows.)

__global__ __launch_bounds__(512) void attn_main2(
    const float* __restrict__ ctx, const unsigned short* __restrict__ whb2,
    const float* __restrict__ qpb, const float* __restrict__ V,
    float* __restrict__ out)
{
    __shared__ unsigned short whs[4 * 16 * 512];   // 64 KiB

    const int tid = threadIdx.x;
    const int bid = blockIdx.x;
    const int h   = (bid >> 3) & 1;
    const int rg  = ((bid >> 4) << 3) + (bid & 7);

    #pragma unroll
    for (int p = 0; p < 8; ++p) {
        int m = p * 512 + tid;
        int u = ((m >> 8) << 9) + (h << 8) + (m & 255);
        *(ushort8*)((char*)whs + (size_t)m * 16) = *(const ushort8*)(whb2 + (size_t)u * 8);
    }
    __syncthreads();

    const int lane = tid & 63;
    const int w    = tid >> 6;
    const int cb   = lane & 15;
    const int g    = lane >> 4;

    const char* bptr = (const char*)whs + lane * 16;
    const float* pL = ctx + ((size_t)rg * 1024 + w * 16 + cb) * (size_t)HID_ + g * 8;
    const int b = rg >> 3;

#define DOSTEP(PA, PB, KK) { \
    short8 aA; \
    aA[0] = f2bf(PA.x); aA[1] = f2bf(PA.y); aA[2] = f2bf(PA.z); aA[3] = f2bf(PA.w); \
    aA[4] = f2bf(PB.x); aA[5] = f2bf(PB.y); aA[6] = f2bf(PB.z); aA[7] = f2bf(PB.w); \
    if ((KK) < 14) { \
        PA = *(const float4*)(pT + ((KK) + 2) * 32); \
        PB = *(const float4*)(pT + ((KK) + 2) * 32 + 4); \
    } else { \
        PA = *(const float4*)(pN + ((KK) - 14) * 32); \
        PB = *(const float4*)(pN + ((KK) - 14) * 32 + 4); \
    } \
    __builtin_amdgcn_sched_barrier(0); \
    _Pragma("unroll") \
    for (int nt = 0; nt < 4; ++nt) { \
        const short8 bb = *(const short8*)(bptr + (KK) * 4096 + nt * 1024); \
        acc[nt] = __builtin_amdgcn_mfma_f32_16x16x32_bf16(aA, bb, acc[nt], 0, 0, 0); \
    } \
    __builtin_amdgcn_sched_barrier(0); }

    float4 E0 = *(const float4*)(pL);        float4 E1 = *(const float4*)(pL + 4);
    float4 O0 = *(const float4*)(pL + 32);   float4 O1 = *(const float4*)(pL + 36);

    #pragma unroll 1
    for (int t = 0; t < 8; ++t) {
        const float* pT = pL + (size_t)t * (128 * HID_);
        const float* pN = (t < 7) ? (pT + 128 * HID_) : pL;

        f32x4 acc[4];
        #pragma unroll
        for (int nt = 0; nt < 4; ++nt) acc[nt] = (f32x4){0.f, 0.f, 0.f, 0.f};

        DOSTEP(E0, E1, 0)   DOSTEP(O0, O1, 1)
        DOSTEP(E0, E1, 2)   DOSTEP(O0, O1, 3)
        DOSTEP(E0, E1, 4)   DOSTEP(O0, O1, 5)
        DOSTEP(E0, E1, 6)   DOSTEP(O0, O1, 7)
        DOSTEP(E0, E1, 8)   DOSTEP(O0, O1, 9)
        DOSTEP(E0, E1, 10)  DOSTEP(O0, O1, 11)
        DOSTEP(E0, E1, 12)  DOSTEP(O0, O1, 13)
        DOSTEP(E0, E1, 14)  DOSTEP(O0, O1, 15)

        // epilogue: tanh(acc + q) . V over this half's 64 cols, reduce over cb
        float s0 = 0.f, s1 = 0.f, s2 = 0.f, s3 = 0.f;
        #pragma unroll
        for (int nt = 0; nt < 4; ++nt) {
            const float q  = qpb[b * D3_ + h * 64 + nt * 16 + cb];
            const float vn = V[h * 64 + nt * 16 + cb];
            s0 += (1.f - 2.f / (__expf(2.f * (acc[nt][0] + q)) + 1.f)) * vn;
            s1 += (1.f - 2.f / (__expf(2.f * (acc[nt][1] + q)) + 1.f)) * vn;
            s2 += (1.f - 2.f / (__expf(2.f * (acc[nt][2] + q)) + 1.f)) * vn;
            s3 += (1.f - 2.f / (__expf(2.f * (acc[nt][3] + q)) + 1.f)) * vn;
        }
        #pragma unroll
        for (int m = 1; m < 16; m <<= 1) {
            s0 += __shfl_xor(s0, m, 64);
            s1 += __shfl_xor(s1, m, 64);
            s2 += __shfl_xor(s2, m, 64);
            s3 += __shfl_xor(s3, m, 64);
        }
        if (cb == 0) {
            const size_t row0 = (size_t)rg * 1024 + (size_t)t * 128 + w * 16;
            const size_t off_ = row0 + (size_t)g * 4;
            // h=0 partial -> att_row slot; h=1 partial -> att slot.
            float* dst = out + (h ? (size_t)BL_ : 0) + off_;
            *(float4*)dst = make_float4(s0, s1, s2, s3);
        }
    }
#undef DOSTEP
}

// ---- combine: out[row] = p0 + p1; out[BL_+row] = 1.0f ----
__global__ void combine(float* __restrict__ out) {
    int i = (blockIdx.x * 256 + threadIdx.x) * 4;   // 262144 rows / 4
    float4 p0 = *(const float4*)(out + i);
    float4 p1 = *(const float4*)(out + BL_ + i);
    *(float4*)(out + i) = make_float4(p0.x + p1.x, p0.y + p1.y,
                                      p0.z + p1.z, p0.w + p1.w);
    *(float4*)(out + BL_ + i) = make_float4(1.f, 1.f, 1.f, 1.f);
}

extern "C" void kernel_launch(void* const* d_in, const int* in_sizes, int n_in,
                              void* d_out, int out_size, void* d_ws, size_t ws_size,
                              hipStream_t stream) {
    const float* inputs  = (const float*)d_in[0];   // (32, 512)
    const float* context = (const float*)d_in[1];   // (32, 8192, 512)
    const float* Wi      = (const float*)d_in[2];   // (128, 512)
    const float* bi      = (const float*)d_in[3];   // (128,)
    const float* Wh      = (const float*)d_in[4];   // (128, 512)
    const float* bh      = (const float*)d_in[5];   // (128,)
    const float* V       = (const float*)d_in[6];   // (128,)
    float* out = (float*)d_out;                     // [att_row 262144][att 262144]

    unsigned short* whb2 = (unsigned short*)d_ws;                  // 128 KiB (permuted)
    float* qpb = (float*)((char*)d_ws + (size_t)D3_ * HID_ * 2);   // 16 KiB

    prep_whb2<<<32, 256, 0, stream>>>(Wh, whb2);
    prep_qpb<<<B_, D3_, 0, stream>>>(inputs, Wi, bi, bh, qpb);
    attn_main2<<<512, 512, 0, stream>>>(context, whb2, qpb, V, out);
    combine<<<256, 256, 0, stream>>>(out);
}